// Round 10
// baseline (144.939 us; speedup 1.0000x reference)
//
#include <hip/hip_runtime.h>
#include <math.h>

#define N_ROWS 262144
#define DIM 64
#define K_CODES 1024
#define ROWS_PER_BLOCK 64
#define EPSF 1e-12f

typedef _Float16 f16x8 __attribute__((ext_vector_type(8)));
typedef float f32x4 __attribute__((ext_vector_type(4)));

// ws layout (floats):
//   wn      : [0, 65536)         normalized codebook fp32 (gather/epilogue)
//   msw     : [65536, 66560)     -0.5 * sum(wn^2) per code
//   partial : [66560, 70656)     per-block loss partials (4096)
//   wf      : halves after that  codebook hi/lo f16, 16x16x32 B-fragment order
//             per 16-code tile t: 2048 halves:
//               [0,512)=hi s0 [512,1024)=hi s1 [1024,1536)=lo s0 [1536,2048)=lo s1
//             within each 512: lane(= g*16 + code%16)*8 + i,  k-dim = s*32+g*8+i
//             +2 uninitialized guard tiles (prefetch targets, never consumed)

__global__ __launch_bounds__(64) void prep_codebook(
    const float* __restrict__ w, float* __restrict__ wn,
    float* __restrict__ msw, _Float16* __restrict__ wf)
{
    int k = blockIdx.x;
    int d = threadIdx.x;
    float v = w[k * DIM + d];
    float sq = v * v;
    #pragma unroll
    for (int off = 32; off; off >>= 1) sq += __shfl_xor(sq, off, 64);
    float n = fmaxf(sqrtf(sq), EPSF);
    float o = v / n;
    wn[k * DIM + d] = o;
    float s2 = o * o;
    #pragma unroll
    for (int off = 32; off; off >>= 1) s2 += __shfl_xor(s2, off, 64);
    if (d == 0) msw[k] = -0.5f * s2;

    _Float16 hi = (_Float16)o;
    _Float16 lo = (_Float16)(o - (float)hi);
    int t = k >> 4, nn = k & 15, s = d >> 5, g = (d >> 3) & 3, i = d & 7;
    size_t base = (size_t)t * 2048 + (size_t)s * 512 + (size_t)(g * 16 + nn) * 8 + i;
    wf[base] = hi;            // h = 0
    wf[base + 1024] = lo;     // h = 1
}

#define MFMA_(A, B, C) C = __builtin_amdgcn_mfma_f32_16x16x32_f16(A, B, C, 0, 0, 0)

// One 16-code tile for this wave's code range: 24 MFMA in 4 independent
// depth-6 chains (one per row-tile), then reload this register set with
// tile TL+2 (depth-2 rotation), then compare.
#define BODY(S0, S1, S2, S3, MV, PP, MVP, TL)                                 \
  {                                                                           \
    f32x4 a0 = {MV, MV, MV, MV};                                              \
    f32x4 a1 = a0, a2 = a0, a3 = a0;                                          \
    __builtin_amdgcn_s_setprio(1);                                            \
    MFMA_(ah[0][0], S0, a0); MFMA_(ah[1][0], S0, a1);                         \
    MFMA_(ah[2][0], S0, a2); MFMA_(ah[3][0], S0, a3);                         \
    MFMA_(ah[0][1], S1, a0); MFMA_(ah[1][1], S1, a1);                         \
    MFMA_(ah[2][1], S1, a2); MFMA_(ah[3][1], S1, a3);                         \
    MFMA_(al[0][0], S0, a0); MFMA_(al[1][0], S0, a1);                         \
    MFMA_(al[2][0], S0, a2); MFMA_(al[3][0], S0, a3);                         \
    MFMA_(al[0][1], S1, a0); MFMA_(al[1][1], S1, a1);                         \
    MFMA_(al[2][1], S1, a2); MFMA_(al[3][1], S1, a3);                         \
    MFMA_(ah[0][0], S2, a0); MFMA_(ah[1][0], S2, a1);                         \
    MFMA_(ah[2][0], S2, a2); MFMA_(ah[3][0], S2, a3);                         \
    MFMA_(ah[0][1], S3, a0); MFMA_(ah[1][1], S3, a1);                         \
    MFMA_(ah[2][1], S3, a2); MFMA_(ah[3][1], S3, a3);                         \
    __builtin_amdgcn_s_setprio(0);                                            \
    S0 = *(const f16x8*)(PP);                                                 \
    S1 = *(const f16x8*)(PP + 512);                                           \
    S2 = *(const f16x8*)(PP + 1024);                                          \
    S3 = *(const f16x8*)(PP + 1536);                                          \
    PP += 4096;                                                               \
    MV = *MVP; MVP += 32;                                                     \
    _Pragma("unroll")                                                         \
    for (int r = 0; r < 4; ++r) {                                             \
      if (a0[r] > best[0][r]) { best[0][r] = a0[r]; bt[0][r] = (TL); }        \
      if (a1[r] > best[1][r]) { best[1][r] = a1[r]; bt[1][r] = (TL); }        \
      if (a2[r] > best[2][r]) { best[2][r] = a2[r]; bt[2][r] = (TL); }        \
      if (a3[r] > best[3][r]) { best[3][r] = a3[r]; bt[3][r] = (TL); }        \
    }                                                                         \
  }

__global__ __launch_bounds__(256, 3) void vq_main_kernel(
    const float* __restrict__ x,
    const float* __restrict__ wn,
    const float* __restrict__ msw,
    const _Float16* __restrict__ wf,
    float* __restrict__ out_q,
    float* __restrict__ out_idx,
    float* __restrict__ partial)
{
    __shared__ float msw_lds[K_CODES + 32];   // +32 guard for last prefetches
    __shared__ float sc_w[4][ROWS_PER_BLOCK];
    __shared__ int   id_w[4][ROWS_PER_BLOCK];
    __shared__ float inv_lds[ROWS_PER_BLOCK];
    __shared__ int   idx_lds[ROWS_PER_BLOCK];
    __shared__ float red[4];

    const int tid = threadIdx.x;              // 0..255 (4 waves)
    const int wv = tid >> 6;                  // wave: owns codes [wv*256, wv*256+256)
    const int lane = tid & 63;
    const int nidx = lane & 15;               // code-within-tile / x-row-within-rowtile
    const int g = lane >> 4;                  // k-group
    const int block_row0 = blockIdx.x * ROWS_PER_BLOCK;

    // ---- prologue: all 4 waves load the SAME 64 rows (4 row-tiles of 16) ----
    // A for 16x16x32: lane = g*16+m holds A[m][k = g*8+i] (+s*32 per kstep)
    f16x8 ah[4][2], al[4][2];
    #pragma unroll
    for (int rt = 0; rt < 4; ++rt) {
        const int arow = block_row0 + rt * 16 + nidx;
        const float* xrow = x + (size_t)arow * DIM + g * 8;
        float xv[2][8];
        #pragma unroll
        for (int s = 0; s < 2; ++s) {
            float4 q0 = *(const float4*)(xrow + s * 32);
            float4 q1 = *(const float4*)(xrow + s * 32 + 4);
            xv[s][0] = q0.x; xv[s][1] = q0.y; xv[s][2] = q0.z; xv[s][3] = q0.w;
            xv[s][4] = q1.x; xv[s][5] = q1.y; xv[s][6] = q1.z; xv[s][7] = q1.w;
        }
        float ss = 0.f;
        #pragma unroll
        for (int s = 0; s < 2; ++s)
            #pragma unroll
            for (int i = 0; i < 8; ++i) ss += xv[s][i] * xv[s][i];
        ss += __shfl_xor(ss, 16, 64);  // sum across the 4 k-groups of this row
        ss += __shfl_xor(ss, 32, 64);
        float nrm = fmaxf(sqrtf(ss), EPSF);
        float inv = 1.0f / nrm;
        if (wv == 0 && g == 0) inv_lds[rt * 16 + nidx] = inv;
        #pragma unroll
        for (int s = 0; s < 2; ++s)
            #pragma unroll
            for (int i = 0; i < 8; ++i) {
                float v = xv[s][i] * inv;
                _Float16 hi = (_Float16)v;
                ah[rt][s][i] = hi;
                al[rt][s][i] = (_Float16)(v - (float)hi);
            }
    }

    // ---- stage msw into LDS (+zero guard), conflict-free 16B/thread ----
    *(float4*)&msw_lds[tid * 4] = *(const float4*)(msw + tid * 4);
    if (tid < 8) {
        float4 z = {0.f, 0.f, 0.f, 0.f};
        *(float4*)&msw_lds[K_CODES + tid * 4] = z;
    }

    // ---- preload this wave's tiles 0,1 into sets A,B; mval via global ----
    const _Float16* bbase = wf + (size_t)(wv * 16) * 2048 + (size_t)lane * 8;
    f16x8 SA0 = *(const f16x8*)(bbase);
    f16x8 SA1 = *(const f16x8*)(bbase + 512);
    f16x8 SA2 = *(const f16x8*)(bbase + 1024);
    f16x8 SA3 = *(const f16x8*)(bbase + 1536);
    f16x8 SB0 = *(const f16x8*)(bbase + 2048);
    f16x8 SB1 = *(const f16x8*)(bbase + 2560);
    f16x8 SB2 = *(const f16x8*)(bbase + 3072);
    f16x8 SB3 = *(const f16x8*)(bbase + 3584);
    const _Float16* pA = bbase + 2 * 2048;
    const _Float16* pB = bbase + 3 * 2048;
    float mvA = msw[wv * 256 + nidx];
    float mvB = msw[wv * 256 + 16 + nidx];
    __syncthreads();
    const float* mvpA = &msw_lds[wv * 256 + 32 + nidx];
    const float* mvpB = &msw_lds[wv * 256 + 48 + nidx];

    float best[4][4];
    int bt[4][4];
    #pragma unroll
    for (int rt = 0; rt < 4; ++rt)
        #pragma unroll
        for (int r = 0; r < 4; ++r) { best[rt][r] = -3.4e38f; bt[rt][r] = 0; }

    // ---- main loop: 16 tiles (this wave's 256 codes), depth-2 rotation ----
    for (int it = 0; it < 8; ++it) {
        BODY(SA0, SA1, SA2, SA3, mvA, pA, mvpA, it * 2)
        BODY(SB0, SB1, SB2, SB3, mvB, pB, mvpB, it * 2 + 1)
    }

    // ---- per-wave argmax reduce across the 16 lanes holding each row ----
    // C 16x16: col = lane&15 (code), row = (lane>>4)*4 + r
    #pragma unroll
    for (int rt = 0; rt < 4; ++rt)
        #pragma unroll
        for (int r = 0; r < 4; ++r) {
            float b = best[rt][r];
            int bi = bt[rt][r] * 16 + nidx;     // code within this wave's range
            #pragma unroll
            for (int off = 1; off <= 8; off <<= 1) {
                float ob = __shfl_xor(b, off, 64);
                int oi = __shfl_xor(bi, off, 64);
                if (ob > b || (ob == b && oi < bi)) { b = ob; bi = oi; }
            }
            if (nidx == 0) {
                const int row = rt * 16 + g * 4 + r;
                sc_w[wv][row] = b;
                id_w[wv][row] = wv * 256 + bi;
            }
        }
    __syncthreads();

    // ---- cross-wave combine (ascending wave order = ascending code index,
    //      strict > keeps the first ⇒ exact first-argmin tie semantics) ----
    if (tid < ROWS_PER_BLOCK) {
        float bs = sc_w[0][tid];
        int bid = id_w[0][tid];
        #pragma unroll
        for (int w = 1; w < 4; ++w) {
            float s2 = sc_w[w][tid];
            int i2 = id_w[w][tid];
            if (s2 > bs) { bs = s2; bid = i2; }
        }
        idx_lds[tid] = bid;
        out_idx[block_row0 + tid] = (float)bid;
    }
    __syncthreads();

    // ---- epilogue: gather fp32 codebook row, write out, loss partial ----
    const int lr = tid >> 2;           // row 0..63
    const int d0 = (tid & 3) * 16;     // 4 threads x 16 floats per row
    const int grow = block_row0 + lr;
    const int ci = idx_lds[lr];
    const float invn = inv_lds[lr];
    const float4* xp = (const float4*)(x + (size_t)grow * DIM + d0);
    const float4* qp = (const float4*)(wn + (size_t)ci * DIM + d0);
    float4* op = (float4*)(out_q + (size_t)grow * DIM + d0);
    float ls = 0.f;
    #pragma unroll
    for (int i = 0; i < 4; ++i) {
        float4 qv = qp[i];
        float4 xv4 = xp[i];
        float e0 = qv.x - xv4.x * invn;
        float e1 = qv.y - xv4.y * invn;
        float e2 = qv.z - xv4.z * invn;
        float e3 = qv.w - xv4.w * invn;
        ls += e0 * e0 + e1 * e1 + e2 * e2 + e3 * e3;
        op[i] = qv;
    }

    float s = ls;
    #pragma unroll
    for (int off = 32; off; off >>= 1) s += __shfl_xor(s, off, 64);
    if (lane == 0) red[wv] = s;
    __syncthreads();
    if (tid == 0) partial[blockIdx.x] = (red[0] + red[1]) + (red[2] + red[3]);
}

__global__ __launch_bounds__(256) void finalize_kernel(
    const float* __restrict__ partial, float* __restrict__ loss_out)
{
    __shared__ float red[4];
    int t = threadIdx.x;
    float s = 0.f;
    #pragma unroll
    for (int i = 0; i < 16; ++i) s += partial[t * 16 + i];  // fixed order
    #pragma unroll
    for (int off = 32; off; off >>= 1) s += __shfl_xor(s, off, 64);
    if ((t & 63) == 0) red[t >> 6] = s;
    __syncthreads();
    if (t == 0)
        *loss_out = 1.25f * (((red[0] + red[1]) + (red[2] + red[3]))
                             / (float)((size_t)N_ROWS * DIM));
}

extern "C" void kernel_launch(void* const* d_in, const int* in_sizes, int n_in,
                              void* d_out, int out_size, void* d_ws, size_t ws_size,
                              hipStream_t stream) {
    const float* x = (const float*)d_in[0];   // [N, D]
    const float* w = (const float*)d_in[1];   // [K, D]
    float* out = (float*)d_out;
    float* ws = (float*)d_ws;

    float* wn      = ws;                                   // 65536 floats
    float* msw     = wn + (size_t)K_CODES * DIM;           // 1024 floats
    float* partial = msw + K_CODES;                        // 4096 floats
    _Float16* wf   = (_Float16*)(partial + 4096);          // 66*2048 halves (incl. 2 guard)

    float* out_q    = out;                                 // [N*D]
    float* out_loss = out + (size_t)N_ROWS * DIM;          // [1]
    float* out_idx  = out_loss + 1;                        // [N]

    prep_codebook<<<K_CODES, 64, 0, stream>>>(w, wn, msw, wf);
    vq_main_kernel<<<N_ROWS / ROWS_PER_BLOCK, 256, 0, stream>>>(
        x, wn, msw, wf, out_q, out_idx, partial);
    finalize_kernel<<<1, 256, 0, stream>>>(partial, out_loss);
}

// Round 11
// 122.805 us; speedup vs baseline: 1.1802x; 1.1802x over previous
//
#include <hip/hip_runtime.h>
#include <math.h>

#define N_ROWS 262144
#define DIM 64
#define K_CODES 1024
#define NT 64                 // code tiles of 16
#define ROWS_PER_BLOCK 128
#define EPSF 1e-12f

typedef _Float16 f16x8 __attribute__((ext_vector_type(8)));
typedef float f32x4 __attribute__((ext_vector_type(4)));

// ws layout (floats):
//   wn      : [0, 65536)         normalized codebook fp32 (gather/epilogue)
//   msw     : [65536, 66560)     -0.5 * sum(wn^2) per code
//   partial : [66560, 68608)     per-block loss partials (2048)
//   wf      : halves after that  codebook hi/lo f16, 16x16x32 B-fragment order
//             per 16-code tile t: 2048 halves:
//               [0,512)=hi s0  [512,1024)=hi s1  [1024,1536)=lo s0  [1536,2048)=lo s1
//             within each 512: lane(= g*16 + code%16)*8 + i,  k-dim = s*32+g*8+i
//             +1 uninitialized guard tile (prefetch target, never consumed)

__global__ __launch_bounds__(64) void prep_codebook(
    const float* __restrict__ w, float* __restrict__ wn,
    float* __restrict__ msw, _Float16* __restrict__ wf)
{
    int k = blockIdx.x;
    int d = threadIdx.x;
    float v = w[k * DIM + d];
    float sq = v * v;
    #pragma unroll
    for (int off = 32; off; off >>= 1) sq += __shfl_xor(sq, off, 64);
    float n = fmaxf(sqrtf(sq), EPSF);
    float o = v / n;
    wn[k * DIM + d] = o;
    float s2 = o * o;
    #pragma unroll
    for (int off = 32; off; off >>= 1) s2 += __shfl_xor(s2, off, 64);
    if (d == 0) msw[k] = -0.5f * s2;

    _Float16 hi = (_Float16)o;
    _Float16 lo = (_Float16)(o - (float)hi);
    // B fragment for 16x16x32: lane = g*16 + n holds k-dims s*32 + g*8 + i
    int t = k >> 4, nn = k & 15, s = d >> 5, g = (d >> 3) & 3, i = d & 7;
    size_t base = (size_t)t * 2048 + (size_t)s * 512 + (size_t)(g * 16 + nn) * 8 + i;
    wf[base] = hi;            // h = 0
    wf[base + 1024] = lo;     // h = 1
}

#define MFMA_(A, B, C) C = __builtin_amdgcn_mfma_f32_16x16x32_f16(A, B, C, 0, 0, 0)

// 12 MFMA: two independent depth-6 chains (row-tile 0 / row-tile 1),
// 3 passes (ah*bh, al*bh, ah*bl) over 2 k-steps each.
#define CLUSTER12(C0, C1, C2, C3, A0, A1)                                     \
    __builtin_amdgcn_s_setprio(1);                                            \
    MFMA_(ah[0][0], C0, A0); MFMA_(ah[1][0], C0, A1);                         \
    MFMA_(ah[0][1], C1, A0); MFMA_(ah[1][1], C1, A1);                         \
    MFMA_(al[0][0], C0, A0); MFMA_(al[1][0], C0, A1);                         \
    MFMA_(al[0][1], C1, A0); MFMA_(al[1][1], C1, A1);                         \
    MFMA_(ah[0][0], C2, A0); MFMA_(ah[1][0], C2, A1);                         \
    MFMA_(ah[0][1], C3, A0); MFMA_(ah[1][1], C3, A1);                         \
    __builtin_amdgcn_s_setprio(0);

// Compare a finished acc pair against the running best (tile index T).
// Strict > keeps the earliest tile => first-argmin tie semantics.
#define COMPARE8(A0, A1, T)                                                   \
    _Pragma("unroll")                                                         \
    for (int r = 0; r < 4; ++r) {                                             \
      if (A0[r] > best[0][r]) { best[0][r] = A0[r]; bt[0][r] = (T); }         \
      if (A1[r] > best[1][r]) { best[1][r] = A1[r]; bt[1][r] = (T); }         \
    }

__global__ __launch_bounds__(256, 4) void vq_main_kernel(
    const float* __restrict__ x,
    const float* __restrict__ wn,
    const float* __restrict__ msw,
    const _Float16* __restrict__ wf,
    float* __restrict__ out_q,
    float* __restrict__ out_idx,
    float* __restrict__ partial)
{
    __shared__ float msw_lds[K_CODES + 16];   // +16 guard for last prefetch
    __shared__ int idx_lds[ROWS_PER_BLOCK];
    __shared__ float inv_lds[ROWS_PER_BLOCK];
    __shared__ float red[4];

    const int tid = threadIdx.x;              // 0..255 (4 waves)
    const int wv = tid >> 6;
    const int lane = tid & 63;
    const int nidx = lane & 15;       // code-within-tile / x-row-within-rowtile
    const int g = lane >> 4;          // k-group
    const int block_row0 = blockIdx.x * ROWS_PER_BLOCK;

    // ---- prologue: 32 rows/wave (2 row-tiles of 16), normalize, hi/lo A-frags ----
    // A for 16x16x32: lane = g*16+m holds A[m][k = g*8+i] (+s*32 per kstep)
    f16x8 ah[2][2], al[2][2];
    #pragma unroll
    for (int rt = 0; rt < 2; ++rt) {
        const int arow = block_row0 + wv * 32 + rt * 16 + nidx;
        const float* xrow = x + (size_t)arow * DIM + g * 8;
        float xv[2][8];
        #pragma unroll
        for (int s = 0; s < 2; ++s) {
            float4 q0 = *(const float4*)(xrow + s * 32);
            float4 q1 = *(const float4*)(xrow + s * 32 + 4);
            xv[s][0] = q0.x; xv[s][1] = q0.y; xv[s][2] = q0.z; xv[s][3] = q0.w;
            xv[s][4] = q1.x; xv[s][5] = q1.y; xv[s][6] = q1.z; xv[s][7] = q1.w;
        }
        float ss = 0.f;
        #pragma unroll
        for (int s = 0; s < 2; ++s)
            #pragma unroll
            for (int i = 0; i < 8; ++i) ss += xv[s][i] * xv[s][i];
        ss += __shfl_xor(ss, 16, 64);  // sum across the 4 k-groups of this row
        ss += __shfl_xor(ss, 32, 64);
        float nrm = fmaxf(sqrtf(ss), EPSF);
        float inv = 1.0f / nrm;
        if (g == 0) inv_lds[wv * 32 + rt * 16 + nidx] = inv;
        #pragma unroll
        for (int s = 0; s < 2; ++s)
            #pragma unroll
            for (int i = 0; i < 8; ++i) {
                float v = xv[s][i] * inv;
                _Float16 hi = (_Float16)v;
                ah[rt][s][i] = hi;
                al[rt][s][i] = (_Float16)(v - (float)hi);
            }
    }

    // ---- stage msw into LDS (+zero guard), conflict-free 16B/thread ----
    *(float4*)&msw_lds[tid * 4] = *(const float4*)(msw + tid * 4);
    if (tid < 4) {
        float4 z = {0.f, 0.f, 0.f, 0.f};
        *(float4*)&msw_lds[K_CODES + tid * 4] = z;
    }

    // ---- preload tile 0 into set A; mval for tile 0 from global ----
    const _Float16* bbase = wf + (size_t)lane * 8;
    f16x8 cbA0 = *(const f16x8*)(bbase);
    f16x8 cbA1 = *(const f16x8*)(bbase + 512);
    f16x8 cbA2 = *(const f16x8*)(bbase + 1024);
    f16x8 cbA3 = *(const f16x8*)(bbase + 1536);
    f16x8 cbB0, cbB1, cbB2, cbB3;
    float mvA = msw[nidx];
    float mvB;
    __syncthreads();

    float best[2][4];
    int bt[2][4];
    #pragma unroll
    for (int rt = 0; rt < 2; ++rt)
        #pragma unroll
        for (int r = 0; r < 4; ++r) { best[rt][r] = -3.4e38f; bt[rt][r] = 0; }

    f32x4 accA0, accA1, accB0, accB1;
    accB0 = f32x4{-3.4e38f, -3.4e38f, -3.4e38f, -3.4e38f};  // first compare is a no-op
    accB1 = accB0;

    // ---- main loop: 64 tiles, no barriers, 2-stage compare pipeline ----
    // body A (tile 2it): load t+1 -> setB, MFMA setA -> accA, compare accB (t-1)
    // body B (tile 2it+1): load t+2 -> setA, MFMA setB -> accB, compare accA (t)
    for (int it = 0; it < NT / 2; ++it) {
        const int t = 2 * it;
        {   // body A
            const _Float16* np = bbase + (size_t)(t + 1) * 2048;
            cbB0 = *(const f16x8*)(np);
            cbB1 = *(const f16x8*)(np + 512);
            cbB2 = *(const f16x8*)(np + 1024);
            cbB3 = *(const f16x8*)(np + 1536);
            mvB = msw_lds[(t + 1) * 16 + nidx];
            accA0 = f32x4{mvA, mvA, mvA, mvA};
            accA1 = accA0;
            CLUSTER12(cbA0, cbA1, cbA2, cbA3, accA0, accA1)
            COMPARE8(accB0, accB1, t - 1)
        }
        {   // body B
            const _Float16* np = bbase + (size_t)(t + 2) * 2048;   // guard at t=62
            cbA0 = *(const f16x8*)(np);
            cbA1 = *(const f16x8*)(np + 512);
            cbA2 = *(const f16x8*)(np + 1024);
            cbA3 = *(const f16x8*)(np + 1536);
            mvA = msw_lds[(t + 2) * 16 + nidx];
            accB0 = f32x4{mvB, mvB, mvB, mvB};
            accB1 = accB0;
            CLUSTER12(cbB0, cbB1, cbB2, cbB3, accB0, accB1)
            COMPARE8(accA0, accA1, t)
        }
    }
    COMPARE8(accB0, accB1, NT - 1)

    // ---- argmax reduce across the 16 lanes holding each row ----
    // C 16x16: col = lane&15 (code), row = (lane>>4)*4 + r
    #pragma unroll
    for (int rt = 0; rt < 2; ++rt)
        #pragma unroll
        for (int r = 0; r < 4; ++r) {
            float b = best[rt][r];
            int bi = bt[rt][r] * 16 + nidx;
            #pragma unroll
            for (int off = 1; off <= 8; off <<= 1) {
                float ob = __shfl_xor(b, off, 64);
                int oi = __shfl_xor(bi, off, 64);
                if (ob > b || (ob == b && oi < bi)) { b = ob; bi = oi; }
            }
            if (nidx == 0)
                idx_lds[wv * 32 + rt * 16 + g * 4 + r] = bi;
        }
    __syncthreads();

    // ---- epilogue: gather fp32 codebook row, write out, loss partial ----
    const int lr = tid >> 1;
    const int grow = block_row0 + lr;
    const int d0 = (tid & 1) * 32;
    const int ci = idx_lds[lr];
    const float invn = inv_lds[lr];
    const float4* xp = (const float4*)(x + (size_t)grow * DIM + d0);
    const float4* qp = (const float4*)(wn + (size_t)ci * DIM + d0);
    float4* op = (float4*)(out_q + (size_t)grow * DIM + d0);
    float ls = 0.f;
    #pragma unroll
    for (int i = 0; i < 8; ++i) {
        float4 qv = qp[i];
        float4 xv4 = xp[i];
        float e0 = qv.x - xv4.x * invn;
        float e1 = qv.y - xv4.y * invn;
        float e2 = qv.z - xv4.z * invn;
        float e3 = qv.w - xv4.w * invn;
        ls += e0 * e0 + e1 * e1 + e2 * e2 + e3 * e3;
        op[i] = qv;
    }
    if (!(tid & 1)) out_idx[grow] = (float)ci;

    float s = ls;
    #pragma unroll
    for (int off = 32; off; off >>= 1) s += __shfl_xor(s, off, 64);
    if (lane == 0) red[wv] = s;
    __syncthreads();
    if (tid == 0) partial[blockIdx.x] = (red[0] + red[1]) + (red[2] + red[3]);
}

__global__ __launch_bounds__(256) void finalize_kernel(
    const float* __restrict__ partial, float* __restrict__ loss_out)
{
    __shared__ float red[4];
    int t = threadIdx.x;
    float s = 0.f;
    #pragma unroll
    for (int i = 0; i < 8; ++i) s += partial[t * 8 + i];  // fixed order
    #pragma unroll
    for (int off = 32; off; off >>= 1) s += __shfl_xor(s, off, 64);
    if ((t & 63) == 0) red[t >> 6] = s;
    __syncthreads();
    if (t == 0)
        *loss_out = 1.25f * (((red[0] + red[1]) + (red[2] + red[3]))
                             / (float)((size_t)N_ROWS * DIM));
}

extern "C" void kernel_launch(void* const* d_in, const int* in_sizes, int n_in,
                              void* d_out, int out_size, void* d_ws, size_t ws_size,
                              hipStream_t stream) {
    const float* x = (const float*)d_in[0];   // [N, D]
    const float* w = (const float*)d_in[1];   // [K, D]
    float* out = (float*)d_out;
    float* ws = (float*)d_ws;

    float* wn      = ws;                                   // 65536 floats
    float* msw     = wn + (size_t)K_CODES * DIM;           // 1024 floats
    float* partial = msw + K_CODES;                        // 2048 floats
    _Float16* wf   = (_Float16*)(partial + 2048);          // 65*2048 halves (incl. guard)

    float* out_q    = out;                                 // [N*D]
    float* out_loss = out + (size_t)N_ROWS * DIM;          // [1]
    float* out_idx  = out_loss + 1;                        // [N]

    prep_codebook<<<K_CODES, 64, 0, stream>>>(w, wn, msw, wf);
    vq_main_kernel<<<N_ROWS / ROWS_PER_BLOCK, 256, 0, stream>>>(
        x, wn, msw, wf, out_q, out_idx, partial);
    finalize_kernel<<<1, 256, 0, stream>>>(partial, out_loss);
}

// Round 12
// 120.175 us; speedup vs baseline: 1.2061x; 1.0219x over previous
//
#include <hip/hip_runtime.h>
#include <math.h>

#define N_ROWS 262144
#define DIM 64
#define K_CODES 1024
#define NT 64                 // code tiles of 16
#define ROWS_PER_BLOCK 128
#define EPSF 1e-12f

typedef _Float16 f16x8 __attribute__((ext_vector_type(8)));
typedef float f32x4 __attribute__((ext_vector_type(4)));

// ws layout (floats):
//   wn      : [0, 65536)         normalized codebook fp32 (gather/epilogue)
//   msw     : [65536, 66560)     -0.5 * sum(wn^2) per code
//   partial : [66560, 68608)     per-block loss partials (2048)
//   wf      : halves after that  codebook hi/lo f16, 16x16x32 B-fragment order
//             per 16-code tile t: 2048 halves:
//               [0,512)=hi s0  [512,1024)=hi s1  [1024,1536)=lo s0  [1536,2048)=lo s1
//             within each 512: lane(= g*16 + code%16)*8 + i,  k-dim = s*32+g*8+i

__global__ __launch_bounds__(64) void prep_codebook(
    const float* __restrict__ w, float* __restrict__ wn,
    float* __restrict__ msw, _Float16* __restrict__ wf)
{
    int k = blockIdx.x;
    int d = threadIdx.x;
    float v = w[k * DIM + d];
    float sq = v * v;
    #pragma unroll
    for (int off = 32; off; off >>= 1) sq += __shfl_xor(sq, off, 64);
    float n = fmaxf(sqrtf(sq), EPSF);
    float o = v / n;
    wn[k * DIM + d] = o;
    float s2 = o * o;
    #pragma unroll
    for (int off = 32; off; off >>= 1) s2 += __shfl_xor(s2, off, 64);
    if (d == 0) msw[k] = -0.5f * s2;

    _Float16 hi = (_Float16)o;
    _Float16 lo = (_Float16)(o - (float)hi);
    // B fragment for 16x16x32: lane = g*16 + n holds k-dims s*32 + g*8 + i
    int t = k >> 4, nn = k & 15, s = d >> 5, g = (d >> 3) & 3, i = d & 7;
    size_t base = (size_t)t * 2048 + (size_t)s * 512 + (size_t)(g * 16 + nn) * 8 + i;
    wf[base] = hi;            // h = 0
    wf[base + 1024] = lo;     // h = 1
}

#define MFMA_(A, B, C) C = __builtin_amdgcn_mfma_f32_16x16x32_f16(A, B, C, 0, 0, 0)

__global__ __launch_bounds__(256, 5) void vq_main_kernel(
    const float* __restrict__ x,
    const float* __restrict__ wn,
    const float* __restrict__ msw,
    const _Float16* __restrict__ wf,
    float* __restrict__ out_q,
    float* __restrict__ out_idx,
    float* __restrict__ partial)
{
    __shared__ _Float16 bbuf[2][2048];        // double-buffered 4 KB code tiles
    __shared__ float msw_lds[K_CODES];
    __shared__ int idx_lds[ROWS_PER_BLOCK];
    __shared__ float inv_lds[ROWS_PER_BLOCK];
    __shared__ float red[4];

    const int tid = threadIdx.x;              // 0..255 (4 waves)
    const int wv = tid >> 6;
    const int lane = tid & 63;
    const int nidx = lane & 15;       // code-within-tile / x-row-within-rowtile
    const int g = lane >> 4;          // k-group
    const int block_row0 = blockIdx.x * ROWS_PER_BLOCK;

    // ---- prologue: 32 rows/wave (2 row-tiles of 16), normalize, hi/lo A-frags ----
    // A for 16x16x32: lane = g*16+m holds A[m][k = g*8+i] (+s*32 per kstep)
    f16x8 ah[2][2], al[2][2];
    #pragma unroll
    for (int rt = 0; rt < 2; ++rt) {
        const int arow = block_row0 + wv * 32 + rt * 16 + nidx;
        const float* xrow = x + (size_t)arow * DIM + g * 8;
        float xv[2][8];
        #pragma unroll
        for (int s = 0; s < 2; ++s) {
            float4 q0 = *(const float4*)(xrow + s * 32);
            float4 q1 = *(const float4*)(xrow + s * 32 + 4);
            xv[s][0] = q0.x; xv[s][1] = q0.y; xv[s][2] = q0.z; xv[s][3] = q0.w;
            xv[s][4] = q1.x; xv[s][5] = q1.y; xv[s][6] = q1.z; xv[s][7] = q1.w;
        }
        float ss = 0.f;
        #pragma unroll
        for (int s = 0; s < 2; ++s)
            #pragma unroll
            for (int i = 0; i < 8; ++i) ss += xv[s][i] * xv[s][i];
        ss += __shfl_xor(ss, 16, 64);  // sum across the 4 k-groups of this row
        ss += __shfl_xor(ss, 32, 64);
        float nrm = fmaxf(sqrtf(ss), EPSF);
        float inv = 1.0f / nrm;
        if (g == 0) inv_lds[wv * 32 + rt * 16 + nidx] = inv;
        #pragma unroll
        for (int s = 0; s < 2; ++s)
            #pragma unroll
            for (int i = 0; i < 8; ++i) {
                float v = xv[s][i] * inv;
                _Float16 hi = (_Float16)v;
                ah[rt][s][i] = hi;
                al[rt][s][i] = (_Float16)(v - (float)hi);
            }
    }

    // ---- stage msw into LDS, conflict-free 16B/thread ----
    *(float4*)&msw_lds[tid * 4] = *(const float4*)(msw + tid * 4);

    // ---- stage tile 0 into bbuf[0]; prefetch tile 1 into regs ----
    const _Float16* gsrc = wf + (size_t)tid * 8;   // 16B per thread per tile
    {
        f16x8 s0 = *(const f16x8*)(gsrc);
        *(f16x8*)&bbuf[0][tid * 8] = s0;
    }
    f16x8 stg = *(const f16x8*)(gsrc + 2048);
    gsrc += 2 * 2048;                               // next load target: tile 2
    __syncthreads();

    float best[2][4];
    int bt[2][4];
    #pragma unroll
    for (int rt = 0; rt < 2; ++rt)
        #pragma unroll
        for (int r = 0; r < 4; ++r) { best[rt][r] = -3.4e38f; bt[rt][r] = 0; }

    // ---- main loop: 64 tiles, LDS double-buffer, one barrier per tile ----
    for (int t = 0; t < NT; ++t) {
        const int cur = t & 1;
        const _Float16* bp = &bbuf[cur][lane * 8];
        f16x8 b0 = *(const f16x8*)(bp);
        f16x8 b1 = *(const f16x8*)(bp + 512);
        f16x8 b2 = *(const f16x8*)(bp + 1024);
        f16x8 b3 = *(const f16x8*)(bp + 1536);
        float mval = msw_lds[t * 16 + nidx];

        f32x4 acc0 = {mval, mval, mval, mval};
        f32x4 acc1 = acc0;
        __builtin_amdgcn_s_setprio(1);
        // 12 MFMA: two independent depth-6 chains (row-tile 0 / row-tile 1)
        MFMA_(ah[0][0], b0, acc0); MFMA_(ah[1][0], b0, acc1);
        MFMA_(ah[0][1], b1, acc0); MFMA_(ah[1][1], b1, acc1);
        MFMA_(al[0][0], b0, acc0); MFMA_(al[1][0], b0, acc1);
        MFMA_(al[0][1], b1, acc0); MFMA_(al[1][1], b1, acc1);
        MFMA_(ah[0][0], b2, acc0); MFMA_(ah[1][0], b2, acc1);
        MFMA_(ah[0][1], b3, acc0); MFMA_(ah[1][1], b3, acc1);
        __builtin_amdgcn_s_setprio(0);

        // write staged tile t+1 (loaded last body) into the other buffer,
        // then issue the load for tile t+2 (T14: issue-early / write-late)
        if (t + 1 < NT) {
            *(f16x8*)&bbuf[cur ^ 1][tid * 8] = stg;
            if (t + 2 < NT) {
                stg = *(const f16x8*)(gsrc);
                gsrc += 2048;
            }
        }

        // compare (strict > keeps earliest tile => first-argmin tie semantics)
        #pragma unroll
        for (int r = 0; r < 4; ++r) {
            if (acc0[r] > best[0][r]) { best[0][r] = acc0[r]; bt[0][r] = t; }
            if (acc1[r] > best[1][r]) { best[1][r] = acc1[r]; bt[1][r] = t; }
        }
        __syncthreads();
    }

    // ---- argmax reduce across the 16 lanes holding each row ----
    // C 16x16: col = lane&15 (code), row = (lane>>4)*4 + r
    #pragma unroll
    for (int rt = 0; rt < 2; ++rt)
        #pragma unroll
        for (int r = 0; r < 4; ++r) {
            float b = best[rt][r];
            int bi = bt[rt][r] * 16 + nidx;
            #pragma unroll
            for (int off = 1; off <= 8; off <<= 1) {
                float ob = __shfl_xor(b, off, 64);
                int oi = __shfl_xor(bi, off, 64);
                if (ob > b || (ob == b && oi < bi)) { b = ob; bi = oi; }
            }
            if (nidx == 0)
                idx_lds[wv * 32 + rt * 16 + g * 4 + r] = bi;
        }
    __syncthreads();

    // ---- epilogue: gather fp32 codebook row, write out, loss partial ----
    const int lr = tid >> 1;
    const int grow = block_row0 + lr;
    const int d0 = (tid & 1) * 32;
    const int ci = idx_lds[lr];
    const float invn = inv_lds[lr];
    const float4* xp = (const float4*)(x + (size_t)grow * DIM + d0);
    const float4* qp = (const float4*)(wn + (size_t)ci * DIM + d0);
    float4* op = (float4*)(out_q + (size_t)grow * DIM + d0);
    float ls = 0.f;
    #pragma unroll
    for (int i = 0; i < 8; ++i) {
        float4 qv = qp[i];
        float4 xv4 = xp[i];
        float e0 = qv.x - xv4.x * invn;
        float e1 = qv.y - xv4.y * invn;
        float e2 = qv.z - xv4.z * invn;
        float e3 = qv.w - xv4.w * invn;
        ls += e0 * e0 + e1 * e1 + e2 * e2 + e3 * e3;
        op[i] = qv;
    }
    if (!(tid & 1)) out_idx[grow] = (float)ci;

    float s = ls;
    #pragma unroll
    for (int off = 32; off; off >>= 1) s += __shfl_xor(s, off, 64);
    if (lane == 0) red[wv] = s;
    __syncthreads();
    if (tid == 0) partial[blockIdx.x] = (red[0] + red[1]) + (red[2] + red[3]);
}

__global__ __launch_bounds__(256) void finalize_kernel(
    const float* __restrict__ partial, float* __restrict__ loss_out)
{
    __shared__ float red[4];
    int t = threadIdx.x;
    float s = 0.f;
    #pragma unroll
    for (int i = 0; i < 8; ++i) s += partial[t * 8 + i];  // fixed order
    #pragma unroll
    for (int off = 32; off; off >>= 1) s += __shfl_xor(s, off, 64);
    if ((t & 63) == 0) red[t >> 6] = s;
    __syncthreads();
    if (t == 0)
        *loss_out = 1.25f * (((red[0] + red[1]) + (red[2] + red[3]))
                             / (float)((size_t)N_ROWS * DIM));
}

extern "C" void kernel_launch(void* const* d_in, const int* in_sizes, int n_in,
                              void* d_out, int out_size, void* d_ws, size_t ws_size,
                              hipStream_t stream) {
    const float* x = (const float*)d_in[0];   // [N, D]
    const float* w = (const float*)d_in[1];   // [K, D]
    float* out = (float*)d_out;
    float* ws = (float*)d_ws;

    float* wn      = ws;                                   // 65536 floats
    float* msw     = wn + (size_t)K_CODES * DIM;           // 1024 floats
    float* partial = msw + K_CODES;                        // 2048 floats
    _Float16* wf   = (_Float16*)(partial + 2048);          // 64*2048 halves

    float* out_q    = out;                                 // [N*D]
    float* out_loss = out + (size_t)N_ROWS * DIM;          // [1]
    float* out_idx  = out_loss + 1;                        // [N]

    prep_codebook<<<K_CODES, 64, 0, stream>>>(w, wn, msw, wf);
    vq_main_kernel<<<N_ROWS / ROWS_PER_BLOCK, 256, 0, stream>>>(
        x, wn, msw, wf, out_q, out_idx, partial);
    finalize_kernel<<<1, 256, 0, stream>>>(partial, out_loss);
}